// Round 5
// baseline (152.335 us; speedup 1.0000x reference)
//
#include <hip/hip_runtime.h>

#define S_LEN 1024
#define NHEAD 12
#define SCALE 0.125f
#define INF_ 1000000.0f

typedef __attribute__((ext_vector_type(8))) short bfrag;
typedef __attribute__((ext_vector_type(4))) float f32x4;
typedef unsigned short ushort_t;
typedef unsigned int uint_t;

__device__ inline ushort_t f2bf(float f) {
    union { float f; uint_t u; } v; v.f = f;
    uint_t u = v.u;
    return (ushort_t)((u + 0x7fffu + ((u >> 16) & 1u)) >> 16);
}
__device__ inline float bf2f(ushort_t h) {
    union { uint_t u; float f; } v; v.u = ((uint_t)h) << 16;
    return v.f;
}

// ---------------- mask pre-pack: clsb bf16, clstt = bf16(cls*tt) ---------
__global__ __launch_bounds__(256) void pack_masks(
    const float* __restrict__ cls, const int* __restrict__ tt,
    ushort_t* __restrict__ clsb, ushort_t* __restrict__ clstt)
{
    int i = blockIdx.x, b = blockIdx.y, tid = threadIdx.x;
    for (int j = tid; j < 1024; j += 256) {
        float c = cls[(size_t)i * 1024 + j];
        if (b == 0) clsb[(size_t)i * 1024 + j] = f2bf(c);
        int v = tt[((size_t)b * 1024 + i) * 1024 + j];
        clstt[((size_t)b * 1024 + i) * 1024 + j] = f2bf(v ? c : 0.0f);
    }
}

// ---------------- weight transpose+convert (batched) ---------------------
struct TJobs { const float* src[5]; ushort_t* dst[5]; };
__global__ __launch_bounds__(256) void tcvt_multi(TJobs jobs) {
    __shared__ float tile[64][65];
    const float* src = jobs.src[blockIdx.z];
    ushort_t* dst = jobs.dst[blockIdx.z];
    int bx = blockIdx.x * 64, by = blockIdx.y * 64;
    for (int e = threadIdx.x; e < 4096; e += 256) {
        int r = e >> 6, c = e & 63;
        tile[r][c] = src[(size_t)(by + r) * 768 + bx + c];
    }
    __syncthreads();
    for (int e = threadIdx.x; e < 4096; e += 256) {
        int r = e >> 6, c = e & 63;
        dst[(size_t)(bx + r) * 768 + by + c] = f2bf(tile[c][r]);
    }
}

// ---------------- batched bf16 MFMA GEMM (register-prefetched) -----------
// mode 0: Cf f32; mode 1: Ch bf16; mode 2: Ch bf16 transposed-per-batch;
// mode 3: three bf16 outputs Ch/Ch2/Ch3 with biases bias/bias2/bias3, *scale.
struct GemmJob {
    const float* Af; const ushort_t* Ah; const ushort_t* BT;
    const float* bias; const float* bias2; const float* bias3;
    float* Cf; ushort_t* Ch; ushort_t* Ch2; ushort_t* Ch3;
    float scale; int mode;
};
struct GemmJobs4 { GemmJob j[4]; };

__global__ __launch_bounds__(256) void gemm_batch(GemmJobs4 jobs) {
    GemmJob jb = jobs.j[blockIdx.z];
    __shared__ __align__(16) ushort_t As[64 * 40];
    __shared__ __align__(16) ushort_t Bs[64 * 40];
    int tid = threadIdx.x;
    int w = tid >> 6, lane = tid & 63, l15 = lane & 15, l4 = lane >> 4;
    int rowBase = blockIdx.x * 64, colBase = blockIdx.y * 64;
    int wm = w >> 1, wn = w & 1;
    f32x4 acc[2][2] = {{{0,0,0,0},{0,0,0,0}},{{0,0,0,0},{0,0,0,0}}};
    int srow = tid >> 2, schunk = (tid & 3) * 8;
    const bool cvt = (jb.Ah == nullptr);

    float4 fa0, fa1; uint4 ra, rb;
    if (cvt) {
        const float* ap = &jb.Af[(size_t)(rowBase + srow) * 768 + schunk];
        fa0 = *(const float4*)ap; fa1 = *(const float4*)(ap + 4);
    } else {
        ra = *(const uint4*)&jb.Ah[(size_t)(rowBase + srow) * 768 + schunk];
    }
    rb = *(const uint4*)&jb.BT[(size_t)(colBase + srow) * 768 + schunk];

    for (int k0 = 0; k0 < 768; k0 += 32) {
        __syncthreads();
        if (cvt) {
            ushort_t tmp[8] = {f2bf(fa0.x), f2bf(fa0.y), f2bf(fa0.z), f2bf(fa0.w),
                               f2bf(fa1.x), f2bf(fa1.y), f2bf(fa1.z), f2bf(fa1.w)};
            *(uint4*)&As[srow * 40 + schunk] = *(const uint4*)tmp;
        } else {
            *(uint4*)&As[srow * 40 + schunk] = ra;
        }
        *(uint4*)&Bs[srow * 40 + schunk] = rb;
        __syncthreads();
        int kn = k0 + 32;
        if (kn < 768) {
            if (cvt) {
                const float* ap = &jb.Af[(size_t)(rowBase + srow) * 768 + kn + schunk];
                fa0 = *(const float4*)ap; fa1 = *(const float4*)(ap + 4);
            } else {
                ra = *(const uint4*)&jb.Ah[(size_t)(rowBase + srow) * 768 + kn + schunk];
            }
            rb = *(const uint4*)&jb.BT[(size_t)(colBase + srow) * 768 + kn + schunk];
        }
        bfrag bfr[2];
#pragma unroll
        for (int nf = 0; nf < 2; ++nf)
            bfr[nf] = *(const bfrag*)&Bs[(wn * 32 + nf * 16 + l15) * 40 + l4 * 8];
#pragma unroll
        for (int mf = 0; mf < 2; ++mf) {
            bfrag af = *(const bfrag*)&As[(wm * 32 + mf * 16 + l15) * 40 + l4 * 8];
#pragma unroll
            for (int nf = 0; nf < 2; ++nf)
                acc[mf][nf] = __builtin_amdgcn_mfma_f32_16x16x32_bf16(af, bfr[nf], acc[mf][nf], 0, 0, 0);
        }
    }
#pragma unroll
    for (int mf = 0; mf < 2; ++mf)
#pragma unroll
        for (int nf = 0; nf < 2; ++nf)
#pragma unroll
            for (int rg = 0; rg < 4; ++rg) {
                int row = rowBase + wm * 32 + mf * 16 + l4 * 4 + rg;
                int col = colBase + wn * 32 + nf * 16 + l15;
                float base = acc[mf][nf][rg];
                if (jb.mode == 3) {
                    size_t idx = (size_t)row * 768 + col;
                    jb.Ch [idx] = f2bf((base + jb.bias [col]) * jb.scale);
                    jb.Ch2[idx] = f2bf((base + jb.bias2[col]) * jb.scale);
                    jb.Ch3[idx] = f2bf((base + jb.bias3[col]) * jb.scale);
                } else {
                    float v = base * jb.scale + (jb.bias ? jb.bias[col] : 0.0f);
                    if (jb.mode == 0) jb.Cf[(size_t)row * 768 + col] = v;
                    else if (jb.mode == 1) jb.Ch[(size_t)row * 768 + col] = f2bf(v);
                    else jb.Ch[((size_t)(row >> 10) * 768 + col) * 1024 + (row & 1023)] = f2bf(v);
                }
            }
}

// ---------------- fused attention: 16 q-rows/block -----------------------
// grid (64, 12, 2), block 256 (4 waves). ~38KB LDS.
__global__ __launch_bounds__(256) void attn_mfma(
    const ushort_t* __restrict__ qw,   // (B*S,768) bf16 (q + rwb*scale)
    const ushort_t* __restrict__ qr,   // (B*S,768) bf16 (q + rrb*scale)
    const ushort_t* __restrict__ qs,   // (B*S,768) bf16 (q + rsb*scale)
    const ushort_t* __restrict__ kh,   // (B*S,768) bf16
    const ushort_t* __restrict__ vt,   // (B,768,S) bf16
    const ushort_t* __restrict__ rh,   // (2064,768) bf16
    const float* __restrict__ seg,     // (2,768)
    const ushort_t* __restrict__ clsb, // (S,S) bf16
    const ushort_t* __restrict__ clstt,// (B,S,S) bf16  cls*tt
    const int* __restrict__ amask,     // (B,S)
    ushort_t* __restrict__ av)         // (B*S,768) bf16
{
    __shared__ __align__(16) ushort_t sQw[16 * 64];
    __shared__ __align__(16) ushort_t sQr[16 * 64];
    __shared__ __align__(16) ushort_t sS[16 * 1024];
    __shared__ ushort_t sAm[1024];
    __shared__ float sDiff[16], sSame[16];
    __shared__ float sMax[16 * 4];
    __shared__ float sSum[16];

    const int tid = threadIdx.x;
    const int w = tid >> 6, lane = tid & 63;
    const int l15 = lane & 15, l4 = lane >> 4;
    const int i0 = blockIdx.x * 16;
    const int n = blockIdx.y;
    const int b = blockIdx.z;

    // ---- stage Q variants (vectorized), seg dots, amask ----
    {
        size_t qoff = (size_t)(b * S_LEN + i0) * 768 + n * 64;
        if (tid < 128) {
            int r = tid >> 3, ch = (tid & 7) * 8;
            *(uint4*)&sQw[r * 64 + ch] = *(const uint4*)&qw[qoff + (size_t)r * 768 + ch];
        } else {
            int t2 = tid - 128;
            int r = t2 >> 3, ch = (t2 & 7) * 8;
            *(uint4*)&sQr[r * 64 + ch] = *(const uint4*)&qr[qoff + (size_t)r * 768 + ch];
        }
        float s0 = seg[n * 64 + lane], s1 = seg[768 + n * 64 + lane];
#pragma unroll
        for (int l = 0; l < 4; ++l) {
            int r = w + 4 * l;
            float qsv = bf2f(qs[qoff + (size_t)r * 768 + lane]);
            float d = qsv * s0, sm = qsv * s1;
#pragma unroll
            for (int off = 32; off >= 1; off >>= 1) {
                d += __shfl_xor(d, off);
                sm += __shfl_xor(sm, off);
            }
            if (lane == 0) { sDiff[r] = d; sSame[r] = sm; }
        }
        for (int j = tid; j < 1024; j += 256)
            sAm[j] = f2bf(-INF_ * (1.0f - (float)amask[b * S_LEN + j]));
    }
    __syncthreads();

    const int tstart = 1009 - i0;  // S - i0 - 15

    // ---- Phase A: pos band = Qr @ Rh^T, scattered into sS (prefetched) --
    {
        bfrag aQr[2];
#pragma unroll
        for (int ks = 0; ks < 2; ++ks)
            aQr[ks] = *(const bfrag*)&sQr[l15 * 64 + ks * 32 + l4 * 8];
        int nt = w;
        bfrag cb0, cb1;
        {
            size_t t = (size_t)(tstart + nt * 16 + l15);
            const ushort_t* rp = &rh[t * 768 + n * 64 + l4 * 8];
            cb0 = *(const bfrag*)rp; cb1 = *(const bfrag*)(rp + 32);
        }
        while (nt < 65) {
            int nn = nt + 4;
            bfrag nb0, nb1;
            if (nn < 65) {
                size_t t = (size_t)(tstart + nn * 16 + l15);
                const ushort_t* rp = &rh[t * 768 + n * 64 + l4 * 8];
                nb0 = *(const bfrag*)rp; nb1 = *(const bfrag*)(rp + 32);
            }
            f32x4 acc = {0, 0, 0, 0};
            acc = __builtin_amdgcn_mfma_f32_16x16x32_bf16(aQr[0], cb0, acc, 0, 0, 0);
            acc = __builtin_amdgcn_mfma_f32_16x16x32_bf16(aQr[1], cb1, acc, 0, 0, 0);
            int tp = nt * 16 + l15;
#pragma unroll
            for (int rg = 0; rg < 4; ++rg) {
                int il = l4 * 4 + rg;
                int j = tp - 15 + il;
                if ((unsigned)j < 1024u)
                    sS[il * 1024 + (j ^ ((il & 7) << 3))] = f2bf(acc[rg]);
            }
            cb0 = nb0; cb1 = nb1; nt = nn;
        }
    }
    __syncthreads();

    // ---- Phase B: content MFMA + epilogue + running row-max ----
    {
        bfrag aQw[2];
#pragma unroll
        for (int ks = 0; ks < 2; ++ks)
            aQw[ks] = *(const bfrag*)&sQw[l15 * 64 + ks * 32 + l4 * 8];
        float diffR[4], dsR[4];
#pragma unroll
        for (int rg = 0; rg < 4; ++rg) {
            int il = l4 * 4 + rg;
            diffR[rg] = sDiff[il];
            dsR[rg] = sSame[il] - sDiff[il];
        }
        float vmax[4] = {-3.0e38f, -3.0e38f, -3.0e38f, -3.0e38f};
        int jt = w;
        bfrag cb0, cb1; ushort_t ccls[4], cctt[4];
        {
            size_t jrow = (size_t)(b * S_LEN + jt * 16 + l15);
            const ushort_t* kp = &kh[jrow * 768 + n * 64 + l4 * 8];
            cb0 = *(const bfrag*)kp; cb1 = *(const bfrag*)(kp + 32);
            int j = jt * 16 + l15;
#pragma unroll
            for (int rg = 0; rg < 4; ++rg) {
                int i = i0 + l4 * 4 + rg;
                ccls[rg] = clsb[(size_t)i * 1024 + j];
                cctt[rg] = clstt[((size_t)b * 1024 + i) * 1024 + j];
            }
        }
        while (jt < 64) {
            int jn = jt + 4;
            bfrag nb0, nb1; ushort_t ncls[4], nctt[4];
            if (jn < 64) {
                size_t jrow = (size_t)(b * S_LEN + jn * 16 + l15);
                const ushort_t* kp = &kh[jrow * 768 + n * 64 + l4 * 8];
                nb0 = *(const bfrag*)kp; nb1 = *(const bfrag*)(kp + 32);
                int j2 = jn * 16 + l15;
#pragma unroll
                for (int rg = 0; rg < 4; ++rg) {
                    int i = i0 + l4 * 4 + rg;
                    ncls[rg] = clsb[(size_t)i * 1024 + j2];
                    nctt[rg] = clstt[((size_t)b * 1024 + i) * 1024 + j2];
                }
            }
            int j = jt * 16 + l15;
            float am = bf2f(sAm[j]);
            f32x4 acc = {0, 0, 0, 0};
            acc = __builtin_amdgcn_mfma_f32_16x16x32_bf16(aQw[0], cb0, acc, 0, 0, 0);
            acc = __builtin_amdgcn_mfma_f32_16x16x32_bf16(aQw[1], cb1, acc, 0, 0, 0);
#pragma unroll
            for (int rg = 0; rg < 4; ++rg) {
                int il = l4 * 4 + rg;
                int sidx = il * 1024 + (j ^ ((il & 7) << 3));
                float pos = bf2f(sS[sidx]);
                float s = acc[rg] + (pos + diffR[rg]) * bf2f(ccls[rg])
                        + dsR[rg] * bf2f(cctt[rg]) + am;
                vmax[rg] = fmaxf(vmax[rg], s);
                sS[sidx] = f2bf(s);
            }
            cb0 = nb0; cb1 = nb1;
#pragma unroll
            for (int rg = 0; rg < 4; ++rg) { ccls[rg] = ncls[rg]; cctt[rg] = nctt[rg]; }
            jt = jn;
        }
        // reduce row-max across the 16 lanes of each l4 group
#pragma unroll
        for (int rg = 0; rg < 4; ++rg) {
#pragma unroll
            for (int off = 1; off < 16; off <<= 1)
                vmax[rg] = fmaxf(vmax[rg], __shfl_xor(vmax[rg], off, 16));
        }
        if (l15 == 0) {
#pragma unroll
            for (int rg = 0; rg < 4; ++rg)
                sMax[(l4 * 4 + rg) * 4 + w] = vmax[rg];
        }
    }
    __syncthreads();

    // ---- single exp+sum pass (linear chunks; elementwise) ----
    {
        int row = tid >> 4, sub = tid & 15;
        float m = fmaxf(fmaxf(sMax[row * 4 + 0], sMax[row * 4 + 1]),
                        fmaxf(sMax[row * 4 + 2], sMax[row * 4 + 3]));
        ushort_t* rp = &sS[row * 1024];
        float sum = 0.0f;
#pragma unroll
        for (int e = 0; e < 8; ++e) {
            int c = sub + 16 * e;
            bfrag v = *(const bfrag*)&rp[c * 8];
            bfrag st;
#pragma unroll
            for (int q = 0; q < 8; ++q) {
                float ev = __expf(bf2f((ushort_t)v[q]) - m);
                sum += ev;
                st[q] = (short)f2bf(ev);
            }
            *(bfrag*)&rp[c * 8] = st;
        }
#pragma unroll
        for (int off = 1; off < 16; off <<= 1) sum += __shfl_xor(sum, off, 16);
        if (sub == 0) sSum[row] = sum;
    }
    __syncthreads();

    // ---- PV: attn_vec = (P @ V) * inv[row] ----
    {
        const ushort_t* vbase = vt + (((size_t)b * NHEAD + n) * 64 + w * 16 + l15) * 1024;
        f32x4 acc = {0, 0, 0, 0};
        bfrag cv = *(const bfrag*)&vbase[l4 * 8];
        for (int ks = 0; ks < 32; ++ks) {
            bfrag nv;
            if (ks < 31) nv = *(const bfrag*)&vbase[(ks + 1) * 32 + l4 * 8];
            bfrag pa = *(const bfrag*)&sS[l15 * 1024 + (((ks * 4 + l4) ^ (l15 & 7)) * 8)];
            acc = __builtin_amdgcn_mfma_f32_16x16x32_bf16(pa, cv, acc, 0, 0, 0);
            cv = nv;
        }
#pragma unroll
        for (int rg = 0; rg < 4; ++rg) {
            int il = l4 * 4 + rg;
            float inv = 1.0f / sSum[il];
            size_t i = (size_t)(b * S_LEN + i0 + il);
            av[i * 768 + n * 64 + w * 16 + l15] = f2bf(acc[rg] * inv);
        }
    }
}

// ---------------- residual + layernorm ----------------------------------
__global__ __launch_bounds__(256) void out_ln_kernel(
    const float* __restrict__ query, const float* __restrict__ attn_out,
    const float* __restrict__ g, const float* __restrict__ beta,
    float* __restrict__ out)
{
    __shared__ float sx[768];
    __shared__ float sRed[4];
    int row = blockIdx.x, tid = threadIdx.x;
    int wave = tid >> 6, lane = tid & 63;
    float lsum = 0.0f;
    for (int c = tid; c < 768; c += 256) {
        float x = query[(size_t)row * 768 + c] + attn_out[(size_t)row * 768 + c];
        sx[c] = x;
        lsum += x;
    }
#pragma unroll
    for (int off = 32; off >= 1; off >>= 1) lsum += __shfl_xor(lsum, off);
    if (lane == 0) sRed[wave] = lsum;
    __syncthreads();
    float mu = (sRed[0] + sRed[1] + sRed[2] + sRed[3]) * (1.0f / 768.0f);
    float lvar = 0.0f;
    for (int c = tid; c < 768; c += 256) {
        float d = sx[c] - mu;
        lvar += d * d;
    }
#pragma unroll
    for (int off = 32; off >= 1; off >>= 1) lvar += __shfl_xor(lvar, off);
    __syncthreads();
    if (lane == 0) sRed[wave] = lvar;
    __syncthreads();
    float var = (sRed[0] + sRed[1] + sRed[2] + sRed[3]) * (1.0f / 768.0f);
    float rstd = rsqrtf(var + 1e-9f);
    for (int c = tid; c < 768; c += 256)
        out[(size_t)row * 768 + c] = (sx[c] - mu) * rstd * g[c] + beta[c];
}

extern "C" void kernel_launch(void* const* d_in, const int* in_sizes, int n_in,
                              void* d_out, int out_size, void* d_ws, size_t ws_size,
                              hipStream_t stream)
{
    const float* query = (const float*)d_in[0];
    const float* key   = (const float*)d_in[1];
    const float* value = (const float*)d_in[2];
    const float* r     = (const float*)d_in[3];
    const float* cls_mask = (const float*)d_in[4];
    const int*   tt_mat   = (const int*)d_in[5];
    const int*   amask    = (const int*)d_in[6];
    const float* wq  = (const float*)d_in[7];
    const float* wk  = (const float*)d_in[8];
    const float* bk  = (const float*)d_in[9];
    const float* wv  = (const float*)d_in[10];
    const float* bv  = (const float*)d_in[11];
    const float* rwb = (const float*)d_in[12];
    const float* rrb = (const float*)d_in[13];
    const float* rsb = (const float*)d_in[14];
    const float* rk  = (const float*)d_in[15];
    const float* seg = (const float*)d_in[16];
    const float* wo  = (const float*)d_in[17];
    const float* bo  = (const float*)d_in[18];
    const float* lng = (const float*)d_in[19];
    const float* lnb = (const float*)d_in[20];
    float* out = (float*)d_out;

    char* W = (char*)d_ws;
    ushort_t* qwv = (ushort_t*)(W + 0);              // +3145728
    ushort_t* qrv = (ushort_t*)(W + 3145728);        // +3145728
    ushort_t* qsv = (ushort_t*)(W + 6291456);        // +3145728
    ushort_t* kh  = (ushort_t*)(W + 9437184);        // +3145728
    ushort_t* vt  = (ushort_t*)(W + 12582912);       // +3145728
    ushort_t* rh  = (ushort_t*)(W + 15728640);       // +3170304 (2064 rows)
    ushort_t* av  = (ushort_t*)(W + 18898944);       // +3145728
    ushort_t* wqT = (ushort_t*)(W + 22044672);       // +1179648
    ushort_t* wkT = (ushort_t*)(W + 23224320);
    ushort_t* wvT = (ushort_t*)(W + 24403968);
    ushort_t* rkT = (ushort_t*)(W + 25583616);
    ushort_t* woT = (ushort_t*)(W + 26763264);       // ends 27942912
    ushort_t* clsb  = (ushort_t*)(W + 27942912);     // +2097152
    ushort_t* clstt = (ushort_t*)(W + 30040064);     // +4194304 -> 34234368
    float* attn_out = (float*)(W + 0);               // aliases qwv..qsv (used after attn)

    hipLaunchKernelGGL(pack_masks, dim3(1024, 2), dim3(256), 0, stream,
                       cls_mask, tt_mat, clsb, clstt);

    TJobs tj;
    tj.src[0] = wq; tj.dst[0] = wqT;
    tj.src[1] = wk; tj.dst[1] = wkT;
    tj.src[2] = wv; tj.dst[2] = wvT;
    tj.src[3] = rk; tj.dst[3] = rkT;
    tj.src[4] = wo; tj.dst[4] = woT;
    hipLaunchKernelGGL(tcvt_multi, dim3(12, 12, 5), dim3(256), 0, stream, tj);

    GemmJobs4 pj;
    pj.j[0] = {query, nullptr, wqT, rwb, rrb, rsb, nullptr, qwv, qrv, qsv, SCALE, 3};
    pj.j[1] = {key,   nullptr, wkT, bk, nullptr, nullptr, nullptr, kh, nullptr, nullptr, 1.0f, 1};
    pj.j[2] = {value, nullptr, wvT, bv, nullptr, nullptr, nullptr, vt, nullptr, nullptr, 1.0f, 2};
    pj.j[3] = {r,     nullptr, rkT, nullptr, nullptr, nullptr, nullptr, rh, nullptr, nullptr, 1.0f, 1};
    hipLaunchKernelGGL(gemm_batch, dim3(32, 12, 4), dim3(256), 0, stream, pj);

    hipLaunchKernelGGL(attn_mfma, dim3(64, 12, 2), dim3(256), 0, stream,
                       qwv, qrv, qsv, kh, vt, rh, seg, clsb, clstt, amask, av);

    GemmJobs4 oj;
    oj.j[0] = {nullptr, av, woT, bo, nullptr, nullptr, attn_out, nullptr, nullptr, nullptr, 1.0f, 0};
    oj.j[1] = oj.j[0]; oj.j[2] = oj.j[0]; oj.j[3] = oj.j[0];
    hipLaunchKernelGGL(gemm_batch, dim3(32, 12, 1), dim3(256), 0, stream, oj);

    hipLaunchKernelGGL(out_ln_kernel, dim3(2048), dim3(256), 0, stream,
                       query, attn_out, lng, lnb, out);
}